// Round 9
// baseline (199.616 us; speedup 1.0000x reference)
//
#include <hip/hip_runtime.h>
#include <math.h>

#define N_NODES 50000
#define N_EDGES 800000
#define C 128
#define NT 3
#define NEG 0.2f
#define CAP 64   // max in-edges per node kept (Poisson(16): max observed degree ~45)

#define GEMM_XB 782          // ceil(N_NODES/64)
#define NCHUNK 782           // edge chunks of 1024 (last partial: 256)

typedef __attribute__((ext_vector_type(8))) short short8;   // 8 bf16 = 4 VGPRs
typedef __attribute__((ext_vector_type(4))) float f32x4;
typedef __attribute__((ext_vector_type(4))) int i32x4;

__device__ __forceinline__ float leaky(float v) { return v > 0.f ? v : NEG * v; }

__device__ __forceinline__ unsigned short f2bf(float f) {
  unsigned int u = __float_as_uint(f);
  u = (u + 0x7FFFu + ((u >> 16) & 1u)) >> 16;   // RNE
  return (unsigned short)u;
}
__device__ __forceinline__ float bf_lo(unsigned int w) { return __uint_as_float(w << 16); }
__device__ __forceinline__ float bf_hi(unsigned int w) { return __uint_as_float(w & 0xFFFF0000u); }

// ---------------- prep: Wt[t][n][k] = bf16(W[t][k][n])  ||  cnt = 0 ----------------
__global__ void k_prep(const float* __restrict__ W, unsigned short* __restrict__ Wt,
                       int* __restrict__ cnt) {
  int bid = blockIdx.x;
  if (bid < 192) {
    int idx = bid * 256 + threadIdx.x;          // 3*128*128 = 49152 elements
    int t = idx >> 14, rem = idx & 16383;
    int n = rem >> 7, k = rem & 127;
    Wt[((size_t)t * C + n) * C + k] = f2bf(W[((size_t)t * C + k) * C + n]);
  } else {
    int i4 = (bid - 192) * 256 + threadIdx.x;   // 12500 int4 = 50000 ints
    if (i4 < N_NODES / 4) ((int4*)cnt)[i4] = make_int4(0, 0, 0, 0);
  }
}

// ---------------- fused SEGREGATED bin || mm (R8 post-mortem refinements) ----------------
// R8 = 61us, WRITE 81MB (predicted 46): residual amp = (a) bin's edge-stream reads
// evicting partially-filled bucket lines from the class L2, (b) mm's 2B/lane xwb
// stores (32B partial segments, 96 instrs/wave/t) draining at every barrier. All
// pipes idle (Occ 25 / VALU 8 / MFMA 2.8) => block critical path is store-drain +
// restage latency. This round:
//  1. bin: __builtin_nontemporal_load on ei/etype (stream bypasses L2, bucket lines
//     stay resident until full -> amp dies; no reuse lost, cross-class reuse was
//     cross-XCD anyway).
//  2. mm: wave-private LDS transpose (each wave owns rows wid*16..+16 x all cols,
//     NO barrier) -> 4 full-line NT dwordx4 stores/wave/t instead of 32 partial
//     global_store_short. Cheap vmcnt drains at barriers.
//  3. mm: T14 prefetch — issue t+1's B-tile loads into regs BEFORE t's MFMA; only
//     the ds_write sits between the two barriers.
//  4. mm: NT loads of x (read-once) to keep L2 for Wt.
__global__ void k_bm(const float* __restrict__ x, const int* __restrict__ node_type,
                     const float* __restrict__ emb, const unsigned short* __restrict__ Wt,
                     unsigned short* __restrict__ xwb,
                     const float* __restrict__ att_src, const float* __restrict__ att_dst,
                     float* __restrict__ a_s, float2* __restrict__ ad_es,
                     const int* __restrict__ ei, const int* __restrict__ etype,
                     int* __restrict__ cnt, int* __restrict__ buckets) {
  __shared__ __align__(16) unsigned short Bs[128][136];   // +8 halfword pad (proven R0 layout)
  __shared__ __align__(16) unsigned short Sc[4][16][136]; // per-wave transpose scratch (16KB)
  const int bid = blockIdx.x;
  const int tid = threadIdx.x;

  if (bid & 1) {
    // ---- bin role (XCDs 1,3,5,7): class owns contiguous 12500-dst range ----
    const int j = bid >> 1;                  // 0..781
    const int c = j & 3;                     // == ((bid%8)>>1): stable per XCD
    const int i = j >> 2;                    // index within class
    const int n_c = (c < 2) ? 196 : 195;     // blocks in this class
    const int dlo = c * 12500, dhi = dlo + 12500;
    for (int cc = i; cc < NCHUNK; cc += n_c) {       // strided chunk coverage
      int e0 = cc * 1024 + tid * 4;
      if (e0 + 4 <= N_EDGES) {               // N_EDGES%4==0: full quad or nothing
        i32x4 s4 = __builtin_nontemporal_load((const i32x4*)(ei + e0));
        i32x4 d4 = __builtin_nontemporal_load((const i32x4*)(ei + N_EDGES + e0));
        i32x4 t4 = __builtin_nontemporal_load((const i32x4*)(etype + e0));
        if (d4[0] >= dlo && d4[0] < dhi) {
          int p = atomicAdd(&cnt[d4[0]], 1);
          if (p < CAP) buckets[(size_t)d4[0] * CAP + p] = t4[0] * N_NODES + s4[0];
        }
        if (d4[1] >= dlo && d4[1] < dhi) {
          int p = atomicAdd(&cnt[d4[1]], 1);
          if (p < CAP) buckets[(size_t)d4[1] * CAP + p] = t4[1] * N_NODES + s4[1];
        }
        if (d4[2] >= dlo && d4[2] < dhi) {
          int p = atomicAdd(&cnt[d4[2]], 1);
          if (p < CAP) buckets[(size_t)d4[2] * CAP + p] = t4[2] * N_NODES + s4[2];
        }
        if (d4[3] >= dlo && d4[3] < dhi) {
          int p = atomicAdd(&cnt[d4[3]], 1);
          if (p < CAP) buckets[(size_t)d4[3] * CAP + p] = t4[3] * N_NODES + s4[3];
        }
      }
    }
    return;
  }

  // ---- mm role (XCDs 0,2,4,6): one 64-row block, t-loop, A in regs once ----
  const int rb = bid >> 1;                   // 0..781
  const int wid = tid >> 6, lane = tid & 63;
  const int m = lane & 15, quad = lane >> 4;
  const int row0 = rb * 64;

  // A fragments in registers, t-invariant: lane (wid,m,quad) owns row wid*16+m,
  // k-chunks {k0i*32 + quad*8 .. +8}. bf16(x + emb[node_type]). x NT (read-once).
  short8 af[4];
  {
    int arow = row0 + wid * 16 + m;
    bool valid = arow < N_NODES;
    const float* xr = x + (size_t)(valid ? arow : 0) * C;   // row 0 if invalid; stores guarded
    int nt = valid ? node_type[arow] : 0;
    const float* er = emb + nt * C;
#pragma unroll
    for (int k0i = 0; k0i < 4; ++k0i) {
      int cb = k0i * 32 + quad * 8;
      f32x4 v0 = __builtin_nontemporal_load((const f32x4*)(xr + cb));
      f32x4 v1 = __builtin_nontemporal_load((const f32x4*)(xr + cb + 4));
      f32x4 e0 = *(const f32x4*)(er + cb);
      f32x4 e1 = *(const f32x4*)(er + cb + 4);
      short8 f;
      f[0] = (short)f2bf(v0[0] + e0[0]);
      f[1] = (short)f2bf(v0[1] + e0[1]);
      f[2] = (short)f2bf(v0[2] + e0[2]);
      f[3] = (short)f2bf(v0[3] + e0[3]);
      f[4] = (short)f2bf(v1[0] + e1[0]);
      f[5] = (short)f2bf(v1[1] + e1[1]);
      f[6] = (short)f2bf(v1[2] + e1[2]);
      f[7] = (short)f2bf(v1[3] + e1[3]);
      af[k0i] = f;
    }
  }

  // stage B for t=0 (32KB, L2-hot: same 96KB Wt read by all mm blocks)
#pragma unroll
  for (int it = 0; it < 8; ++it) {
    int c = tid + it * 256;
    int n = c >> 4, kc = c & 15;
    *(i32x4*)&Bs[n][kc * 8] = *(const i32x4*)(Wt + (size_t)n * C + kc * 8);
  }
  __syncthreads();

  for (int t = 0; t < NT; ++t) {
    // T14: prefetch t+1's B tile into regs BEFORE compute (hidden under MFMA+epilogue)
    i32x4 pfr[8];
    if (t + 1 < NT) {
      const unsigned short* Wtt = Wt + (size_t)(t + 1) * C * C;
#pragma unroll
      for (int it = 0; it < 8; ++it) {
        int c = tid + it * 256;
        int n = c >> 4, kc = c & 15;
        pfr[it] = *(const i32x4*)(Wtt + (size_t)n * C + kc * 8);
      }
    }

    f32x4 acc[8] = {};
#pragma unroll
    for (int k0i = 0; k0i < 4; ++k0i) {
      int k0 = k0i * 32;
#pragma unroll
      for (int j = 0; j < 8; ++j) {
        short8 b = *(const short8*)&Bs[j * 16 + m][k0 + quad * 8];
        acc[j] = __builtin_amdgcn_mfma_f32_16x16x32_bf16(af[k0i], b, acc[j], 0, 0, 0);
      }
    }

    // epilogue: attention logits + wave-private LDS transpose of the 16x128 tile
    float ps[4] = {}, pd[4] = {};
#pragma unroll
    for (int j = 0; j < 8; ++j) {
      float as = att_src[t * C + j * 16 + m];
      float ad = att_dst[t * C + j * 16 + m];
#pragma unroll
      for (int reg = 0; reg < 4; ++reg) {
        float v = acc[j][reg];
        Sc[wid][quad * 4 + reg][j * 16 + m] = f2bf(v);   // wave-local, no barrier
        ps[reg] += v * as;
        pd[reg] += v * ad;
      }
    }
#pragma unroll
    for (int off = 1; off < 16; off <<= 1) {
#pragma unroll
      for (int reg = 0; reg < 4; ++reg) {
        ps[reg] += __shfl_xor(ps[reg], off);
        pd[reg] += __shfl_xor(pd[reg], off);
      }
    }
    if (m == 0) {
#pragma unroll
      for (int reg = 0; reg < 4; ++reg) {
        int row = row0 + wid * 16 + quad * 4 + reg;
        if (row < N_NODES) {
          int idx = t * N_NODES + row;
          a_s[idx] = ps[reg];
          ad_es[idx] = make_float2(pd[reg], leaky(ps[reg] + pd[reg]));  // {a_d, e_self}
        }
      }
    }
    // coalesced full-line NT stores: 4 passes x (4 rows x 256B = 1KB per instr)
#pragma unroll
    for (int p = 0; p < 4; ++p) {
      int rloc = p * 4 + (lane >> 4);
      int row = row0 + wid * 16 + rloc;
      if (row < N_NODES) {
        i32x4 v = *(const i32x4*)&Sc[wid][rloc][(lane & 15) * 8];
        __builtin_nontemporal_store(v, (i32x4*)(xwb + ((size_t)t * N_NODES + row) * C + (lane & 15) * 8));
      }
    }

    if (t + 1 < NT) {
      __syncthreads();          // all waves done reading Bs
#pragma unroll
      for (int it = 0; it < 8; ++it) {
        int c = tid + it * 256;
        int n = c >> 4, kc = c & 15;
        *(i32x4*)&Bs[n][kc * 8] = pfr[it];
      }
      __syncthreads();
    }
  }
}

// ---------------- per node (1 wave): w per lane, denom via wave-reduce, out = self+bias+sum coef*xw ----------------
// Serial loop uses wave-uniform (readfirstlane) bucket-row loads + LDS coefficient
// broadcast instead of 2 ds_bpermute per edge.
__global__ void k_gather(const int* __restrict__ cnt, const int* __restrict__ buckets,
                         const unsigned short* __restrict__ xwb,
                         const float* __restrict__ a_s, const float2* __restrict__ ad_es,
                         const float* __restrict__ bias, float* __restrict__ out) {
  __shared__ float wcs[4][64];
  int wid = threadIdx.x >> 6;
  int lane = threadIdx.x & 63;
  int i = blockIdx.x * 4 + wid;                       // grid covers N exactly (12500*4)
  int iu = __builtin_amdgcn_readfirstlane(i);         // wave-uniform node id
  const int* __restrict__ brow = buckets + (size_t)iu * CAP;
  int n = cnt[iu];
  if (n > CAP) n = CAP;

  int idxl = 0;
  if (lane < n) idxl = brow[lane];                    // coalesced 256B wave load
  int tl = idxl >= 2 * N_NODES ? 2 : (idxl >= N_NODES ? 1 : 0);
  float as = a_s[idxl];                               // random 4B, L2-resident (600 KB)
  float2 am = ad_es[tl * N_NODES + iu];               // 3 distinct addrs per wave
  float wl = (lane < n) ? __expf(leaky(as + am.x) - am.y) : 0.f;

  // per-type denominators: butterfly-reduce w by type
  float s0 = tl == 0 ? wl : 0.f;
  float s1 = tl == 1 ? wl : 0.f;
  float s2 = tl == 2 ? wl : 0.f;
#pragma unroll
  for (int off = 1; off < 64; off <<= 1) {
    s0 += __shfl_xor(s0, off);
    s1 += __shfl_xor(s1, off);
    s2 += __shfl_xor(s2, off);
  }
  float inv3[NT] = {1.f / (s0 + 1.f), 1.f / (s1 + 1.f), 1.f / (s2 + 1.f)};  // w_self == 1
  wcs[wid][lane] = wl * inv3[tl];   // premultiplied coefficient, broadcast via LDS

  // self-loop (coef = inv3[t]) + bias
  float acc0 = 0.f, acc1 = 0.f;   // cols 2*lane, 2*lane+1
#pragma unroll
  for (int t = 0; t < NT; ++t) {
    int idx = t * N_NODES + iu;
    float coef = inv3[t];
    unsigned int w = ((const unsigned int*)(xwb + (size_t)idx * C))[lane];
    float2 b2 = ((const float2*)(bias + t * C))[lane];
    acc0 += coef * bf_lo(w) + b2.x;
    acc1 += coef * bf_hi(w) + b2.y;
  }

  const unsigned int* xwu = (const unsigned int*)xwb;
  int j = 0;
  for (; j + 16 <= n; j += 16) {   // 16-way MLP
    float ac0 = 0.f, ac1 = 0.f;
#pragma unroll
    for (int k = 0; k < 16; ++k) {
      int idx = brow[j + k];          // wave-uniform load (L1-hot line)
      float c = wcs[wid][j + k];      // LDS broadcast, conflict-free
      unsigned int v = xwu[(size_t)idx * (C / 2) + lane];
      ac0 += c * bf_lo(v);
      ac1 += c * bf_hi(v);
    }
    acc0 += ac0; acc1 += ac1;
  }
  for (; j + 8 <= n; j += 8) {     // 8-way MLP
    float ac0 = 0.f, ac1 = 0.f;
#pragma unroll
    for (int k = 0; k < 8; ++k) {
      int idx = brow[j + k];
      float c = wcs[wid][j + k];
      unsigned int v = xwu[(size_t)idx * (C / 2) + lane];
      ac0 += c * bf_lo(v);
      ac1 += c * bf_hi(v);
    }
    acc0 += ac0; acc1 += ac1;
  }
  for (; j < n; ++j) {
    int idx = brow[j];
    float c = wcs[wid][j];
    unsigned int v = xwu[(size_t)idx * (C / 2) + lane];
    acc0 += c * bf_lo(v);
    acc1 += c * bf_hi(v);
  }
  ((float2*)(out + (size_t)iu * C))[lane] = make_float2(acc0, acc1);
}

extern "C" void kernel_launch(void* const* d_in, const int* in_sizes, int n_in,
                              void* d_out, int out_size, void* d_ws, size_t ws_size,
                              hipStream_t stream) {
  const float* x       = (const float*)d_in[0];
  const int* edge_idx  = (const int*)d_in[1];
  const int* edge_type = (const int*)d_in[2];
  const int* node_type = (const int*)d_in[3];
  const float* emb     = (const float*)d_in[4];
  const float* W       = (const float*)d_in[5];
  const float* att_src = (const float*)d_in[6];
  const float* att_dst = (const float*)d_in[7];
  const float* bias    = (const float*)d_in[8];
  float* out = (float*)d_out;

  // workspace layout (~53 MB)
  unsigned short* xwb = (unsigned short*)d_ws;                 // 3*N*C bf16 (38.4 MB)
  unsigned short* Wt  = xwb + (size_t)NT * N_NODES * C;        // 3*C*C bf16 (96 KB)
  float*  a_s   = (float*)(Wt + (size_t)NT * C * C);           // 3*N (600 KB)
  float2* ad_es = (float2*)(a_s + (size_t)NT * N_NODES);       // 3*N float2 (1.2 MB)
  int*    cnt   = (int*)(ad_es + (size_t)NT * N_NODES);        // N ints
  int*    buckets = (int*)(cnt + N_NODES);                     // N*CAP int (12.8 MB)

  k_prep<<<192 + 49, 256, 0, stream>>>(W, Wt, cnt);

  k_bm<<<2 * GEMM_XB, 256, 0, stream>>>(x, node_type, emb, Wt, xwb, att_src, att_dst,
                                        a_s, ad_es, edge_idx, edge_type, cnt, buckets);

  k_gather<<<N_NODES / 4, 256, 0, stream>>>(cnt, buckets, xwb, a_s, ad_es, bias, out);
}

// Round 12
// 180.346 us; speedup vs baseline: 1.1068x; 1.1068x over previous
//
#include <hip/hip_runtime.h>
#include <math.h>

#define N_NODES 50000
#define N_EDGES 800000
#define C 128
#define NT 3
#define NEG 0.2f
#define CAP 64   // max in-edges per node kept (Poisson(16): max observed degree ~45)

#define GEMM_XB 782          // ceil(N_NODES/64)
#define NCHUNK 782           // edge chunks of 1024 (last partial: 256)

typedef __attribute__((ext_vector_type(8))) short short8;   // 8 bf16 = 4 VGPRs
typedef __attribute__((ext_vector_type(4))) float f32x4;

__device__ __forceinline__ float leaky(float v) { return v > 0.f ? v : NEG * v; }

__device__ __forceinline__ unsigned short f2bf(float f) {
  unsigned int u = __float_as_uint(f);
  u = (u + 0x7FFFu + ((u >> 16) & 1u)) >> 16;   // RNE
  return (unsigned short)u;
}
__device__ __forceinline__ float bf_lo(unsigned int w) { return __uint_as_float(w << 16); }
__device__ __forceinline__ float bf_hi(unsigned int w) { return __uint_as_float(w & 0xFFFF0000u); }

// ---------------- prep: Wt[t][n][k] = bf16(W[t][k][n])  ||  cnt = 0 ----------------
__global__ void k_prep(const float* __restrict__ W, unsigned short* __restrict__ Wt,
                       int* __restrict__ cnt) {
  int bid = blockIdx.x;
  if (bid < 192) {
    int idx = bid * 256 + threadIdx.x;          // 3*128*128 = 49152 elements
    int t = idx >> 14, rem = idx & 16383;
    int n = rem >> 7, k = rem & 127;
    Wt[((size_t)t * C + n) * C + k] = f2bf(W[((size_t)t * C + k) * C + n]);
  } else {
    int i4 = (bid - 192) * 256 + threadIdx.x;   // 12500 int4 = 50000 ints
    if (i4 < N_NODES / 4) ((int4*)cnt)[i4] = make_int4(0, 0, 0, 0);
  }
}

// ---------------- fused SEGREGATED bin || mm (exact R8 kernel, harness-verified 173.3us) ----------------
// R10/R11 both failed with "container failed twice" on the R8+T14-prefetch binary;
// diagnostic revert to the byte-exact R8 build (known passing) to isolate infra vs
// binary. Standing structure:
//  - segregation: bin on odd-bid XCDs, mm on even (R0 lesson: overlap is free only
//    when the two traffic classes own disjoint L2s; R7's mixing = serial sum).
//  - bin partitioned: class c=(bid>>1)&3 owns dsts [c*12500,+12500) -> buckets+cnt
//    L2-resident per class (R5 lesson: kills 16x dirty-line bounce).
//  - mm: A in regs once (R1), B via LDS staged per t (R2), t-loop reusing A (R3).
// Scaling note (R4-R9): bin and mm are each ~43-45us standalone FULL-device and
// 61us fused on HALF-device each -> fabric/latency-limited, not CU-limited;
// placement rebalancing is exhausted. Remaining levers are small (R9's bundle of
// NT loads/stores + LDS transpose + 52KB LDS regressed to 71us; reverted).
__global__ void k_bm(const float* __restrict__ x, const int* __restrict__ node_type,
                     const float* __restrict__ emb, const unsigned short* __restrict__ Wt,
                     unsigned short* __restrict__ xwb,
                     const float* __restrict__ att_src, const float* __restrict__ att_dst,
                     float* __restrict__ a_s, float2* __restrict__ ad_es,
                     const int* __restrict__ ei, const int* __restrict__ etype,
                     int* __restrict__ cnt, int* __restrict__ buckets) {
  __shared__ unsigned short Bs[128][136];   // +8 halfword pad (proven R0 layout)
  const int bid = blockIdx.x;
  const int tid = threadIdx.x;

  if (bid & 1) {
    // ---- bin role (XCDs 1,3,5,7): class owns contiguous 12500-dst range ----
    const int j = bid >> 1;                  // 0..781
    const int c = j & 3;                     // == ((bid%8)>>1): stable per XCD
    const int i = j >> 2;                    // index within class
    const int n_c = (c < 2) ? 196 : 195;     // blocks in this class
    const int dlo = c * 12500, dhi = dlo + 12500;
    for (int cc = i; cc < NCHUNK; cc += n_c) {       // strided chunk coverage
      int e0 = cc * 1024 + tid * 4;
      if (e0 + 4 <= N_EDGES) {               // N_EDGES%4==0: full quad or nothing
        int4 s4 = *(const int4*)(ei + e0);
        int4 d4 = *(const int4*)(ei + N_EDGES + e0);
        int4 t4 = *(const int4*)(etype + e0);
        if (d4.x >= dlo && d4.x < dhi) {
          int p = atomicAdd(&cnt[d4.x], 1);
          if (p < CAP) buckets[(size_t)d4.x * CAP + p] = t4.x * N_NODES + s4.x;
        }
        if (d4.y >= dlo && d4.y < dhi) {
          int p = atomicAdd(&cnt[d4.y], 1);
          if (p < CAP) buckets[(size_t)d4.y * CAP + p] = t4.y * N_NODES + s4.y;
        }
        if (d4.z >= dlo && d4.z < dhi) {
          int p = atomicAdd(&cnt[d4.z], 1);
          if (p < CAP) buckets[(size_t)d4.z * CAP + p] = t4.z * N_NODES + s4.z;
        }
        if (d4.w >= dlo && d4.w < dhi) {
          int p = atomicAdd(&cnt[d4.w], 1);
          if (p < CAP) buckets[(size_t)d4.w * CAP + p] = t4.w * N_NODES + s4.w;
        }
      }
    }
    return;
  }

  // ---- mm role (XCDs 0,2,4,6): one 64-row block, t-loop, A in regs once ----
  const int rb = bid >> 1;                   // 0..781
  const int wid = tid >> 6, lane = tid & 63;
  const int m = lane & 15, quad = lane >> 4;
  const int row0 = rb * 64;

  // A fragments in registers, t-invariant: lane (wid,m,quad) owns row wid*16+m,
  // k-chunks {k0i*32 + quad*8 .. +8}. bf16(x + emb[node_type]).
  short8 af[4];
  {
    int arow = row0 + wid * 16 + m;
    bool valid = arow < N_NODES;
    const float* xr = x + (size_t)(valid ? arow : 0) * C;   // row 0 if invalid; stores guarded
    int nt = valid ? node_type[arow] : 0;
    const float* er = emb + nt * C;
#pragma unroll
    for (int k0i = 0; k0i < 4; ++k0i) {
      int cb = k0i * 32 + quad * 8;
      float4 v0 = *(const float4*)(xr + cb);
      float4 v1 = *(const float4*)(xr + cb + 4);
      float4 e0 = *(const float4*)(er + cb);
      float4 e1 = *(const float4*)(er + cb + 4);
      short8 f;
      f[0] = (short)f2bf(v0.x + e0.x);
      f[1] = (short)f2bf(v0.y + e0.y);
      f[2] = (short)f2bf(v0.z + e0.z);
      f[3] = (short)f2bf(v0.w + e0.w);
      f[4] = (short)f2bf(v1.x + e1.x);
      f[5] = (short)f2bf(v1.y + e1.y);
      f[6] = (short)f2bf(v1.z + e1.z);
      f[7] = (short)f2bf(v1.w + e1.w);
      af[k0i] = f;
    }
  }

  // stage B for t=0 (32KB, L2-hot: same 96KB Wt read by all mm blocks)
#pragma unroll
  for (int it = 0; it < 8; ++it) {
    int c = tid + it * 256;
    int n = c >> 4, kc = c & 15;
    *(uint4*)&Bs[n][kc * 8] = *(const uint4*)(Wt + (size_t)n * C + kc * 8);
  }
  __syncthreads();

  for (int t = 0; t < NT; ++t) {
    f32x4 acc[8] = {};
#pragma unroll
    for (int k0i = 0; k0i < 4; ++k0i) {
      int k0 = k0i * 32;
#pragma unroll
      for (int j = 0; j < 8; ++j) {
        short8 b = *(const short8*)&Bs[j * 16 + m][k0 + quad * 8];
        acc[j] = __builtin_amdgcn_mfma_f32_16x16x32_bf16(af[k0i], b, acc[j], 0, 0, 0);
      }
    }

    // epilogue: write xw (bf16) + fused attention logits (registers/shuffles only)
    float ps[4] = {}, pd[4] = {};
#pragma unroll
    for (int j = 0; j < 8; ++j) {
      float as = att_src[t * C + j * 16 + m];
      float ad = att_dst[t * C + j * 16 + m];
#pragma unroll
      for (int reg = 0; reg < 4; ++reg) {
        int row = row0 + wid * 16 + quad * 4 + reg;
        float v = acc[j][reg];
        if (row < N_NODES) xwb[((size_t)t * N_NODES + row) * C + j * 16 + m] = f2bf(v);
        ps[reg] += v * as;
        pd[reg] += v * ad;
      }
    }
#pragma unroll
    for (int off = 1; off < 16; off <<= 1) {
#pragma unroll
      for (int reg = 0; reg < 4; ++reg) {
        ps[reg] += __shfl_xor(ps[reg], off);
        pd[reg] += __shfl_xor(pd[reg], off);
      }
    }
    if (m == 0) {
#pragma unroll
      for (int reg = 0; reg < 4; ++reg) {
        int row = row0 + wid * 16 + quad * 4 + reg;
        if (row < N_NODES) {
          int idx = t * N_NODES + row;
          a_s[idx] = ps[reg];
          ad_es[idx] = make_float2(pd[reg], leaky(ps[reg] + pd[reg]));  // {a_d, e_self}
        }
      }
    }

    if (t + 1 < NT) {
      __syncthreads();          // all waves done reading Bs
      const unsigned short* Wtt = Wt + (size_t)(t + 1) * C * C;
#pragma unroll
      for (int it = 0; it < 8; ++it) {
        int c = tid + it * 256;
        int n = c >> 4, kc = c & 15;
        *(uint4*)&Bs[n][kc * 8] = *(const uint4*)(Wtt + (size_t)n * C + kc * 8);
      }
      __syncthreads();
    }
  }
}

// ---------------- per node (1 wave): w per lane, denom via wave-reduce, out = self+bias+sum coef*xw ----------------
// Serial loop uses wave-uniform (readfirstlane) bucket-row loads + LDS coefficient
// broadcast instead of 2 ds_bpermute per edge.
__global__ void k_gather(const int* __restrict__ cnt, const int* __restrict__ buckets,
                         const unsigned short* __restrict__ xwb,
                         const float* __restrict__ a_s, const float2* __restrict__ ad_es,
                         const float* __restrict__ bias, float* __restrict__ out) {
  __shared__ float wcs[4][64];
  int wid = threadIdx.x >> 6;
  int lane = threadIdx.x & 63;
  int i = blockIdx.x * 4 + wid;                       // grid covers N exactly (12500*4)
  int iu = __builtin_amdgcn_readfirstlane(i);         // wave-uniform node id
  const int* __restrict__ brow = buckets + (size_t)iu * CAP;
  int n = cnt[iu];
  if (n > CAP) n = CAP;

  int idxl = 0;
  if (lane < n) idxl = brow[lane];                    // coalesced 256B wave load
  int tl = idxl >= 2 * N_NODES ? 2 : (idxl >= N_NODES ? 1 : 0);
  float as = a_s[idxl];                               // random 4B, L2-resident (600 KB)
  float2 am = ad_es[tl * N_NODES + iu];               // 3 distinct addrs per wave
  float wl = (lane < n) ? __expf(leaky(as + am.x) - am.y) : 0.f;

  // per-type denominators: butterfly-reduce w by type
  float s0 = tl == 0 ? wl : 0.f;
  float s1 = tl == 1 ? wl : 0.f;
  float s2 = tl == 2 ? wl : 0.f;
#pragma unroll
  for (int off = 1; off < 64; off <<= 1) {
    s0 += __shfl_xor(s0, off);
    s1 += __shfl_xor(s1, off);
    s2 += __shfl_xor(s2, off);
  }
  float inv3[NT] = {1.f / (s0 + 1.f), 1.f / (s1 + 1.f), 1.f / (s2 + 1.f)};  // w_self == 1
  wcs[wid][lane] = wl * inv3[tl];   // premultiplied coefficient, broadcast via LDS

  // self-loop (coef = inv3[t]) + bias
  float acc0 = 0.f, acc1 = 0.f;   // cols 2*lane, 2*lane+1
#pragma unroll
  for (int t = 0; t < NT; ++t) {
    int idx = t * N_NODES + iu;
    float coef = inv3[t];
    unsigned int w = ((const unsigned int*)(xwb + (size_t)idx * C))[lane];
    float2 b2 = ((const float2*)(bias + t * C))[lane];
    acc0 += coef * bf_lo(w) + b2.x;
    acc1 += coef * bf_hi(w) + b2.y;
  }

  const unsigned int* xwu = (const unsigned int*)xwb;
  int j = 0;
  for (; j + 16 <= n; j += 16) {   // 16-way MLP
    float ac0 = 0.f, ac1 = 0.f;
#pragma unroll
    for (int k = 0; k < 16; ++k) {
      int idx = brow[j + k];          // wave-uniform load (L1-hot line)
      float c = wcs[wid][j + k];      // LDS broadcast, conflict-free
      unsigned int v = xwu[(size_t)idx * (C / 2) + lane];
      ac0 += c * bf_lo(v);
      ac1 += c * bf_hi(v);
    }
    acc0 += ac0; acc1 += ac1;
  }
  for (; j + 8 <= n; j += 8) {     // 8-way MLP
    float ac0 = 0.f, ac1 = 0.f;
#pragma unroll
    for (int k = 0; k < 8; ++k) {
      int idx = brow[j + k];
      float c = wcs[wid][j + k];
      unsigned int v = xwu[(size_t)idx * (C / 2) + lane];
      ac0 += c * bf_lo(v);
      ac1 += c * bf_hi(v);
    }
    acc0 += ac0; acc1 += ac1;
  }
  for (; j < n; ++j) {
    int idx = brow[j];
    float c = wcs[wid][j];
    unsigned int v = xwu[(size_t)idx * (C / 2) + lane];
    acc0 += c * bf_lo(v);
    acc1 += c * bf_hi(v);
  }
  ((float2*)(out + (size_t)iu * C))[lane] = make_float2(acc0, acc1);
}

extern "C" void kernel_launch(void* const* d_in, const int* in_sizes, int n_in,
                              void* d_out, int out_size, void* d_ws, size_t ws_size,
                              hipStream_t stream) {
  const float* x       = (const float*)d_in[0];
  const int* edge_idx  = (const int*)d_in[1];
  const int* edge_type = (const int*)d_in[2];
  const int* node_type = (const int*)d_in[3];
  const float* emb     = (const float*)d_in[4];
  const float* W       = (const float*)d_in[5];
  const float* att_src = (const float*)d_in[6];
  const float* att_dst = (const float*)d_in[7];
  const float* bias    = (const float*)d_in[8];
  float* out = (float*)d_out;

  // workspace layout (~53 MB)
  unsigned short* xwb = (unsigned short*)d_ws;                 // 3*N*C bf16 (38.4 MB)
  unsigned short* Wt  = xwb + (size_t)NT * N_NODES * C;        // 3*C*C bf16 (96 KB)
  float*  a_s   = (float*)(Wt + (size_t)NT * C * C);           // 3*N (600 KB)
  float2* ad_es = (float2*)(a_s + (size_t)NT * N_NODES);       // 3*N float2 (1.2 MB)
  int*    cnt   = (int*)(ad_es + (size_t)NT * N_NODES);        // N ints
  int*    buckets = (int*)(cnt + N_NODES);                     // N*CAP int (12.8 MB)

  k_prep<<<192 + 49, 256, 0, stream>>>(W, Wt, cnt);

  k_bm<<<2 * GEMM_XB, 256, 0, stream>>>(x, node_type, emb, Wt, xwb, att_src, att_dst,
                                        a_s, ad_es, edge_idx, edge_type, cnt, buckets);

  k_gather<<<N_NODES / 4, 256, 0, stream>>>(cnt, buckets, xwb, a_s, ad_es, bias, out);
}